// Round 4
// baseline (379.905 us; speedup 1.0000x reference)
//
#include <hip/hip_runtime.h>
#include <math.h>

#define B_ 4
#define S_ 2048
#define D_ 128
#define EPSF 1e-5f
#define PSB 144   // Ps row stride bytes (64 bf16 + 8 pad): 16B-aligned

typedef __attribute__((ext_vector_type(8))) short short8;
typedef __attribute__((ext_vector_type(4))) float f32x4;

static __device__ __forceinline__ unsigned short f2bf(float f) {
    unsigned u = __float_as_uint(f);
    return (unsigned short)((u + 0x7fffu + ((u >> 16) & 1u)) >> 16);
}

static __device__ __forceinline__ void gload_lds16(const void* g, void* l) {
    __builtin_amdgcn_global_load_lds((const __attribute__((address_space(1))) unsigned*)g,
                                     (__attribute__((address_space(3))) unsigned*)l, 16, 0, 0);
}

// ws bytes: [0,32K) qn | [32K,64K) kn | [64K,96K) lws | [96K,97K) cnt(256 int)
//           | Qb(2M) | Kb(2M) | Vtb(2M) | Osum(4M) | Pws(32M bf16)

__global__ __launch_bounds__(256) void convqk_kernel(const float* __restrict__ q,
                                                     const float* __restrict__ k,
                                                     float* __restrict__ qn, float* __restrict__ kn,
                                                     float* __restrict__ lws,
                                                     unsigned* __restrict__ Qb, unsigned* __restrict__ Kb,
                                                     float* __restrict__ Osum, int* __restrict__ cnt) {
    int row = blockIdx.x * 4 + (threadIdx.x >> 6);   // one wave per row, 16384 rows
    int lane = threadIdx.x & 63;
    // zero the O accumulator (4096*256 = exactly B*S*D floats) and group counters
    Osum[(size_t)blockIdx.x * 256 + threadIdx.x] = 0.f;
    if (blockIdx.x == 0) cnt[threadIdx.x] = 0;
    const int NR = B_ * S_;
    bool isQ = row < NR;
    int r = isQ ? row : row - NR;
    float2 v = ((const float2*)(isQ ? q : k))[(size_t)r * 64 + lane];
    unsigned pk = (unsigned)f2bf(v.x) | ((unsigned)f2bf(v.y) << 16);
    float nrm = v.x * v.x + v.y * v.y;
#pragma unroll
    for (int m = 1; m <= 32; m <<= 1) nrm += __shfl_xor(nrm, m, 64);
    if (isQ) {
        Qb[(size_t)r * 64 + lane] = pk;              // plain row-major
        if (lane == 0) qn[r] = nrm;
        if (lane == 1) lws[r] = 0.f;                 // zero l accumulator
    } else {
        int c = lane >> 2;                           // 16B chunk 0..15
        int cs = c ^ (r & 7);                        // bake LDS bank swizzle into global layout
        Kb[(size_t)r * 64 + cs * 4 + (lane & 3)] = pk;
        if (lane == 0) kn[r] = nrm;
    }
}

// V -> bf16, transposed 64-key tiles: [tile(b*32+t)][d=128][8 x 16B key-chunks], chunk-swizzled
__global__ __launch_bounds__(256) void convv_kernel(const float* __restrict__ v, uint4* __restrict__ Vtb) {
    __shared__ unsigned short Vs[64 * 132];          // padded stride 132
    int b = blockIdx.x >> 5;
    int t = blockIdx.x & 31;
    int tid = threadIdx.x;
    const float* src = v + ((size_t)b * S_ + t * 64) * D_;
    int d4 = tid & 31, key0 = tid >> 5;
#pragma unroll
    for (int it = 0; it < 8; ++it) {
        int key = key0 + it * 8;
        float4 f = *(const float4*)(src + (size_t)key * D_ + d4 * 4);
        unsigned short* dst = &Vs[key * 132 + d4 * 4];
        dst[0] = f2bf(f.x); dst[1] = f2bf(f.y); dst[2] = f2bf(f.z); dst[3] = f2bf(f.w);
    }
    __syncthreads();
    uint4* tile = Vtb + (size_t)blockIdx.x * (128 * 8);
    int d = tid & 127;
    int cl = tid >> 7;
#pragma unroll
    for (int it = 0; it < 4; ++it) {
        int c = cl + it * 2;                         // key-chunk 0..7
        int kb = c * 8;
        unsigned short e0 = Vs[(kb + 0) * 132 + d], e1 = Vs[(kb + 1) * 132 + d];
        unsigned short e2 = Vs[(kb + 2) * 132 + d], e3 = Vs[(kb + 3) * 132 + d];
        unsigned short e4 = Vs[(kb + 4) * 132 + d], e5 = Vs[(kb + 5) * 132 + d];
        unsigned short e6 = Vs[(kb + 6) * 132 + d], e7 = Vs[(kb + 7) * 132 + d];
        uint4 o;
        o.x = (unsigned)e0 | ((unsigned)e1 << 16);
        o.y = (unsigned)e2 | ((unsigned)e3 << 16);
        o.z = (unsigned)e4 | ((unsigned)e5 << 16);
        o.w = (unsigned)e6 | ((unsigned)e7 << 16);
        tile[d * 8 + (c ^ (d & 7))] = o;
    }
}

// ===================== v3: BN=64, 4 blocks/CU, fused tail =====================

__global__ __launch_bounds__(512, 8) void hattn3_kernel(
    const unsigned short* __restrict__ Qb, const char* __restrict__ Kb, const char* __restrict__ Vtb,
    const float* __restrict__ qn, const float* __restrict__ kn,
    const float* __restrict__ cp, const float* __restrict__ betap, const float* __restrict__ biasp,
    float* __restrict__ lws, float* __restrict__ Osum, int* __restrict__ cnt,
    uint4* __restrict__ Pws, float* __restrict__ hout, float* __restrict__ wout) {

    __shared__ __align__(1024) char smem[38272];
    char* KsB = smem;                                // 16 KB: 64 key-rows x 256B (swizzled)
    char* VtB = smem + 16384;                        // 16 KB: 128 d-rows x 128B (swizzled)
    char* PsB = smem + 32768;                        // 4608 B: 32 rows x 144B
    float* yn_s  = (float*)(smem + 37376);           // 64 f
    float* gy_s  = (float*)(smem + 37632);           // 64 f
    float* xn_s  = (float*)(smem + 37888);           // 32 f (reused as linv_s in tail)
    float* rx_s  = (float*)(smem + 38016);           // 32 f
    float* l_row = (float*)(smem + 38144);           // 32 f
    __shared__ int sflag;

    const int tid = threadIdx.x;
    const int lane = tid & 63, wave = tid >> 6;
    const int wm = wave & 1, wn = wave >> 1;         // wm: 16-row half; wn: 16-col / 32-d slice
    const int lm = lane & 15, quad = lane >> 4;

    const int gid = blockIdx.x;
    const int b = (gid >> 1) & 3;                    // batch pinned to XCD pair (xcd = gid&7)
    const int th = ((gid >> 3) & 1) * 2 + (gid & 1); // t-quarter 0..3
    const int rb = gid >> 4;                         // 0..63
    const int s0 = rb * 32;
    const int g = (b << 6) | rb;                     // group id 0..255
    const size_t bS = (size_t)b * S_;

    const float cc = cp[0], beta = betap[0], bias = biasp[0];
    const float beta_pos = fmaxf(beta, 0.f) + log1pf(__expf(-fabsf(beta)));
    const float sqrt_c = sqrtf(cc);
    const float bneg = -beta_pos / sqrt_c;           // p = 2^(bneg*log2(w) + bias2)
    const float bias2 = -bias * 1.442695040888963f;
    const float onepe = 1.f + EPSF;
    const float c2 = 2.f * cc;

    if (tid < 32) {
        float xn = qn[bS + s0 + tid];
        xn_s[tid] = xn;
        rx_s[tid] = c2 * __builtin_amdgcn_rcpf(1.f - cc * xn);
        l_row[tid] = 0.f;
    }

    // Q A-frags in registers (A: m=lane&15, k=quad*8+j)
    short8 aq[4];
    {
        const unsigned short* qrow = Qb + (bS + s0 + wm * 16 + lm) * D_;
#pragma unroll
        for (int ks = 0; ks < 4; ++ks)
            aq[ks] = *(const short8*)(qrow + ks * 32 + quad * 8);
    }

    f32x4 o0 = {0.f, 0.f, 0.f, 0.f}, o1 = {0.f, 0.f, 0.f, 0.f};

    const char* KbBase = Kb + bS * 256;
    const char* VtBase = Vtb + (size_t)b * 32 * 16384;

    const int n0 = wn * 16 + lm;                     // QK B key-row
    const int d0 = wn * 32 + lm, d1 = d0 + 16;       // PV B d-rows
    const int col = wn * 16 + lm;                    // score column

    for (int it = 0; it < 8; ++it) {
        int t = th * 8 + it;
        int t0 = t * 64;
        __syncthreads();
        // async stage K (16KB) + Vt (16KB), verbatim linear, pre-swizzled
        {
            const char* ksrc = KbBase + (size_t)t0 * 256;
            const char* vsrc = VtBase + (size_t)t * 16384;
            int off = tid * 16;
            gload_lds16(ksrc + off, KsB + off);
            gload_lds16(ksrc + off + 8192, KsB + off + 8192);
            gload_lds16(vsrc + off, VtB + off);
            gload_lds16(vsrc + off + 8192, VtB + off + 8192);
            if (tid < 64) {
                float yn = kn[bS + t0 + tid];
                yn_s[tid] = yn;
                gy_s[tid] = __builtin_amdgcn_rcpf(1.f - cc * yn);
            }
        }
        __syncthreads();

        // ---- S = Q K^T (wave tile 16x16) ----
        f32x4 acc = {0.f, 0.f, 0.f, 0.f};
#pragma unroll
        for (int ks = 0; ks < 4; ++ks) {
            int c = ks * 4 + quad;
            short8 bf = *(const short8*)(KsB + n0 * 256 + ((c ^ (n0 & 7)) * 16));
            acc = __builtin_amdgcn_mfma_f32_16x16x32_bf16(aq[ks], bf, acc, 0, 0, 0);
        }

        // ---- dist -> p (unnormalized; scores <= 0) ----
        float ynv = yn_s[col], gyv = gy_s[col];
#pragma unroll
        for (int r = 0; r < 4; ++r) {
            int row = wm * 16 + quad * 4 + r;        // C/D: row=(lane>>4)*4+reg, col=lane&15
            float diff = fmaf(-2.f, acc[r], xn_s[row] + ynv);
            float arg = fmaf(diff * gyv, rx_s[row], 1.f);
            arg = fmaxf(arg, onepe);
            float w = arg + sqrtf(fmaf(arg, arg, -1.f));
            float p = __builtin_amdgcn_exp2f(fmaf(bneg, __builtin_amdgcn_logf(w), bias2));
            *(unsigned short*)(PsB + row * PSB + col * 2) = f2bf(p);
            float s = p;
#pragma unroll
            for (int m = 1; m <= 8; m <<= 1) s += __shfl_xor(s, m, 64);
            if (lm == 0) atomicAdd(&l_row[row], s);
        }
        __syncthreads();

        // ---- coalesced P tile -> global bf16 (32x64 = 4KB = 256 uint4) ----
        if (tid < 256) {
            int row = tid >> 3, ch = tid & 7;
            uint4 pv = *(const uint4*)(PsB + row * PSB + ch * 16);
            Pws[(((bS + s0 + row) * S_ + t0) >> 3) + ch] = pv;
        }

        // ---- O += P V (wave tile 16 rows x 32 d) ----
#pragma unroll
        for (int ks = 0; ks < 2; ++ks) {
            short8 ap = *(const short8*)(PsB + (wm * 16 + lm) * PSB + ks * 64 + quad * 16);
            int c = ks * 4 + quad;
            short8 v0 = *(const short8*)(VtB + d0 * 128 + ((c ^ (d0 & 7)) * 16));
            short8 v1 = *(const short8*)(VtB + d1 * 128 + ((c ^ (d1 & 7)) * 16));
            o0 = __builtin_amdgcn_mfma_f32_16x16x32_bf16(ap, v0, o0, 0, 0, 0);
            o1 = __builtin_amdgcn_mfma_f32_16x16x32_bf16(ap, v1, o1, 0, 0, 0);
        }
    }

    // ---- combine partials: device-scope atomics ----
    float* ob = Osum + (bS + s0) * D_;
#pragma unroll
    for (int r = 0; r < 4; ++r) {
        int row = wm * 16 + quad * 4 + r;
        atomicAdd(&ob[(size_t)row * D_ + wn * 32 + lm], o0[r]);
        atomicAdd(&ob[(size_t)row * D_ + wn * 32 + 16 + lm], o1[r]);
    }
    if (tid < 32) atomicAdd(&lws[bS + s0 + tid], l_row[tid]);
    __syncthreads();                                  // all waves' global ops drained (vmcnt(0))
    if (tid == 0) {
        __threadfence();                              // release: L2 writeback, device visibility
        sflag = (atomicAdd(&cnt[g], 1) == 3);
    }
    __syncthreads();
    if (!sflag) return;

    // ===== tail: last finisher of the group does epilogue + W expansion =====
    __threadfence();                                  // acquire: invalidate stale cache
    float* linv_s = xn_s;                             // reuse
    if (tid < 32) linv_s[tid] = 1.f / lws[bS + s0 + tid];
    __syncthreads();

    // exp-map epilogue: wave w handles rows w*4..w*4+4
#pragma unroll
    for (int rr = 0; rr < 4; ++rr) {
        int row = wave * 4 + rr;
        float2 x2 = ((const float2*)(ob + (size_t)row * D_))[lane];
        float linv = linv_s[row];
        float x0 = x2.x * linv, x1 = x2.y * linv;
        float np = x0 * x0 + x1 * x1;
#pragma unroll
        for (int m = 1; m <= 32; m <<= 1) np += __shfl_xor(np, m, 64);
        float vn = fmaxf(sqrtf(np), EPSF);
        float a = sqrt_c * vn;
        float t = 1.f - 2.f / (__expf(2.f * a) + 1.f);   // tanh(a)
        float sc = t / a;
        float2 o = {x0 * sc, x1 * sc};
        ((float2*)(hout + (bS + s0 + row) * D_))[lane] = o;
    }

    // W expansion: 32 rows x 2048 cols, bf16 -> fp32/l
    {
        size_t base = ((bS + s0) * (size_t)S_) >> 3;     // uint4 index
        for (int j = 0; j < 16; ++j) {
            int idx = tid + j * 512;                     // 0..8191
            int row = idx >> 8;
            float linv = linv_s[row];
            uint4 u = Pws[base + idx];
            float4 f0, f1;
            f0.x = __uint_as_float(u.x << 16) * linv;
            f0.y = __uint_as_float(u.x & 0xffff0000u) * linv;
            f0.z = __uint_as_float(u.y << 16) * linv;
            f0.w = __uint_as_float(u.y & 0xffff0000u) * linv;
            f1.x = __uint_as_float(u.z << 16) * linv;
            f1.y = __uint_as_float(u.z & 0xffff0000u) * linv;
            f1.z = __uint_as_float(u.w << 16) * linv;
            f1.w = __uint_as_float(u.w & 0xffff0000u) * linv;
            float4* outp = (float4*)wout + (base + idx) * 2;
            outp[0] = f0;
            outp[1] = f1;
        }
    }
}

// ===================== launch =====================

extern "C" void kernel_launch(void* const* d_in, const int* in_sizes, int n_in,
                              void* d_out, int out_size, void* d_ws, size_t ws_size,
                              hipStream_t stream) {
    const float* q    = (const float*)d_in[0];
    const float* k    = (const float*)d_in[1];
    const float* v    = (const float*)d_in[2];
    const float* c    = (const float*)d_in[3];
    const float* beta = (const float*)d_in[4];
    const float* ab   = (const float*)d_in[5];

    float* out  = (float*)d_out;
    float* hout = out;                          // (B,S,D)
    float* wout = out + (size_t)B_ * S_ * D_;   // (B,S,S)

    char* wsb = (char*)d_ws;
    float* qn  = (float*)wsb;
    float* kn  = (float*)(wsb + 32768);
    float* lws = (float*)(wsb + 65536);
    int*   cnt = (int*)(wsb + 98304);
    const size_t QB_OFF = 99328;
    const size_t KB_OFF = QB_OFF + 2097152;
    const size_t VT_OFF = KB_OFF + 2097152;
    const size_t OS_OFF = VT_OFF + 2097152;
    const size_t PW_OFF = OS_OFF + (size_t)B_ * S_ * D_ * 4;     // 4 MB Osum
    // NEED = PW_OFF + 32MB bf16 P  (~42.1 MB; round-3 proved ws >= 46.1 MB)

    unsigned* Qb = (unsigned*)(wsb + QB_OFF);
    unsigned* Kb = (unsigned*)(wsb + KB_OFF);
    uint4*   Vtb = (uint4*)(wsb + VT_OFF);
    float*  Osum = (float*)(wsb + OS_OFF);
    uint4*   Pws = (uint4*)(wsb + PW_OFF);

    convqk_kernel<<<4096, 256, 0, stream>>>(q, k, qn, kn, lws, Qb, Kb, Osum, cnt);
    convv_kernel<<<128, 256, 0, stream>>>(v, Vtb);
    hattn3_kernel<<<1024, 512, 0, stream>>>((const unsigned short*)Qb, (const char*)Kb,
                                            (const char*)Vtb, qn, kn, c, beta, ab,
                                            lws, Osum, cnt, Pws, hout, wout);
}

// Round 5
// 158.906 us; speedup vs baseline: 2.3908x; 2.3908x over previous
//
#include <hip/hip_runtime.h>
#include <math.h>

#define B_ 4
#define S_ 2048
#define D_ 128
#define EPSF 1e-5f
#define PSB 144   // Ps row stride bytes (64 bf16 + 8 pad): 16B-aligned

typedef __attribute__((ext_vector_type(8))) short short8;
typedef __attribute__((ext_vector_type(4))) float f32x4;

static __device__ __forceinline__ unsigned short f2bf(float f) {
    unsigned u = __float_as_uint(f);
    return (unsigned short)((u + 0x7fffu + ((u >> 16) & 1u)) >> 16);
}

static __device__ __forceinline__ void gload_lds16(const void* g, void* l) {
    __builtin_amdgcn_global_load_lds((const __attribute__((address_space(1))) unsigned*)g,
                                     (__attribute__((address_space(3))) unsigned*)l, 16, 0, 0);
}

// ws bytes: [0,32K) qn | [32K,64K) kn | [64K,96K) lws
//           | Qb(2M) | Kb(2M) | Vtb(2M) | Osum(4M) | Pws(32M bf16)

__global__ __launch_bounds__(256) void convqk_kernel(const float* __restrict__ q,
                                                     const float* __restrict__ k,
                                                     float* __restrict__ qn, float* __restrict__ kn,
                                                     float* __restrict__ lws,
                                                     unsigned* __restrict__ Qb, unsigned* __restrict__ Kb,
                                                     float* __restrict__ Osum) {
    int row = blockIdx.x * 4 + (threadIdx.x >> 6);   // one wave per row, 16384 rows
    int lane = threadIdx.x & 63;
    // zero the O accumulator (4096*256 = exactly B*S*D floats)
    Osum[(size_t)blockIdx.x * 256 + threadIdx.x] = 0.f;
    const int NR = B_ * S_;
    bool isQ = row < NR;
    int r = isQ ? row : row - NR;
    float2 v = ((const float2*)(isQ ? q : k))[(size_t)r * 64 + lane];
    unsigned pk = (unsigned)f2bf(v.x) | ((unsigned)f2bf(v.y) << 16);
    float nrm = v.x * v.x + v.y * v.y;
#pragma unroll
    for (int m = 1; m <= 32; m <<= 1) nrm += __shfl_xor(nrm, m, 64);
    if (isQ) {
        Qb[(size_t)r * 64 + lane] = pk;              // plain row-major
        if (lane == 0) qn[r] = nrm;
        if (lane == 1) lws[r] = 0.f;                 // zero l accumulator
    } else {
        int c = lane >> 2;                           // 16B chunk 0..15
        int cs = c ^ (r & 7);                        // bake LDS bank swizzle into global layout
        Kb[(size_t)r * 64 + cs * 4 + (lane & 3)] = pk;
        if (lane == 0) kn[r] = nrm;
    }
}

// V -> bf16, transposed 64-key tiles: [tile(b*32+t)][d=128][8 x 16B key-chunks], chunk-swizzled
__global__ __launch_bounds__(256) void convv_kernel(const float* __restrict__ v, uint4* __restrict__ Vtb) {
    __shared__ unsigned short Vs[64 * 132];          // padded stride 132
    int b = blockIdx.x >> 5;
    int t = blockIdx.x & 31;
    int tid = threadIdx.x;
    const float* src = v + ((size_t)b * S_ + t * 64) * D_;
    int d4 = tid & 31, key0 = tid >> 5;
#pragma unroll
    for (int it = 0; it < 8; ++it) {
        int key = key0 + it * 8;
        float4 f = *(const float4*)(src + (size_t)key * D_ + d4 * 4);
        unsigned short* dst = &Vs[key * 132 + d4 * 4];
        dst[0] = f2bf(f.x); dst[1] = f2bf(f.y); dst[2] = f2bf(f.z); dst[3] = f2bf(f.w);
    }
    __syncthreads();
    uint4* tile = Vtb + (size_t)blockIdx.x * (128 * 8);
    int d = tid & 127;
    int cl = tid >> 7;
#pragma unroll
    for (int it = 0; it < 4; ++it) {
        int c = cl + it * 2;                         // key-chunk 0..7
        int kb = c * 8;
        unsigned short e0 = Vs[(kb + 0) * 132 + d], e1 = Vs[(kb + 1) * 132 + d];
        unsigned short e2 = Vs[(kb + 2) * 132 + d], e3 = Vs[(kb + 3) * 132 + d];
        unsigned short e4 = Vs[(kb + 4) * 132 + d], e5 = Vs[(kb + 5) * 132 + d];
        unsigned short e6 = Vs[(kb + 6) * 132 + d], e7 = Vs[(kb + 7) * 132 + d];
        uint4 o;
        o.x = (unsigned)e0 | ((unsigned)e1 << 16);
        o.y = (unsigned)e2 | ((unsigned)e3 << 16);
        o.z = (unsigned)e4 | ((unsigned)e5 << 16);
        o.w = (unsigned)e6 | ((unsigned)e7 << 16);
        tile[d * 8 + (c ^ (d & 7))] = o;
    }
}

// ===================== v4: BN=64, 4-way t-split, 4 blocks/CU target =====================

__global__ __launch_bounds__(512, 4) void hattn4_kernel(
    const unsigned short* __restrict__ Qb, const char* __restrict__ Kb, const char* __restrict__ Vtb,
    const float* __restrict__ qn, const float* __restrict__ kn,
    const float* __restrict__ cp, const float* __restrict__ betap, const float* __restrict__ biasp,
    float* __restrict__ lws, float* __restrict__ Osum, uint4* __restrict__ Pws) {

    __shared__ __align__(1024) char smem[38272];
    char* KsB = smem;                                // 16 KB: 64 key-rows x 256B (swizzled)
    char* VtB = smem + 16384;                        // 16 KB: 128 d-rows x 128B (swizzled)
    char* PsB = smem + 32768;                        // 4608 B: 32 rows x 144B
    float* yn_s  = (float*)(smem + 37376);           // 64 f
    float* gy_s  = (float*)(smem + 37632);           // 64 f
    float* xn_s  = (float*)(smem + 37888);           // 32 f
    float* rx_s  = (float*)(smem + 38016);           // 32 f
    float* l_row = (float*)(smem + 38144);           // 32 f

    const int tid = threadIdx.x;
    const int lane = tid & 63, wave = tid >> 6;
    const int wm = wave & 1, wn = wave >> 1;         // wm: 16-row half; wn: 16-col / 32-d slice
    const int lm = lane & 15, quad = lane >> 4;

    const int gid = blockIdx.x;
    const int b = (gid >> 1) & 3;                    // batch pinned to XCD pair (xcd = gid&7)
    const int th = ((gid >> 3) & 1) * 2 + (gid & 1); // t-quarter 0..3
    const int rb = gid >> 4;                         // 0..63
    const int s0 = rb * 32;
    const size_t bS = (size_t)b * S_;

    const float cc = cp[0], beta = betap[0], bias = biasp[0];
    const float beta_pos = fmaxf(beta, 0.f) + log1pf(__expf(-fabsf(beta)));
    const float sqrt_c = sqrtf(cc);
    const float bneg = -beta_pos / sqrt_c;           // p = 2^(bneg*log2(w) + bias2)
    const float bias2 = -bias * 1.442695040888963f;
    const float onepe = 1.f + EPSF;
    const float c2 = 2.f * cc;

    if (tid < 32) {
        float xn = qn[bS + s0 + tid];
        xn_s[tid] = xn;
        rx_s[tid] = c2 * __builtin_amdgcn_rcpf(1.f - cc * xn);
        l_row[tid] = 0.f;
    }

    // Q A-frags in registers (A: m=lane&15, k=quad*8+j)
    short8 aq[4];
    {
        const unsigned short* qrow = Qb + (bS + s0 + wm * 16 + lm) * D_;
#pragma unroll
        for (int ks = 0; ks < 4; ++ks)
            aq[ks] = *(const short8*)(qrow + ks * 32 + quad * 8);
    }

    f32x4 o0 = {0.f, 0.f, 0.f, 0.f}, o1 = {0.f, 0.f, 0.f, 0.f};

    const char* KbBase = Kb + bS * 256;
    const char* VtBase = Vtb + (size_t)b * 32 * 16384;

    const int n0 = wn * 16 + lm;                     // QK B key-row
    const int d0 = wn * 32 + lm, d1 = d0 + 16;       // PV B d-rows
    const int col = wn * 16 + lm;                    // score column

    for (int it = 0; it < 8; ++it) {
        int t = th * 8 + it;
        int t0 = t * 64;
        __syncthreads();
        // async stage K (16KB) + Vt (16KB), verbatim linear, pre-swizzled
        {
            const char* ksrc = KbBase + (size_t)t0 * 256;
            const char* vsrc = VtBase + (size_t)t * 16384;
            int off = tid * 16;
            gload_lds16(ksrc + off, KsB + off);
            gload_lds16(ksrc + off + 8192, KsB + off + 8192);
            gload_lds16(vsrc + off, VtB + off);
            gload_lds16(vsrc + off + 8192, VtB + off + 8192);
            if (tid < 64) {
                float yn = kn[bS + t0 + tid];
                yn_s[tid] = yn;
                gy_s[tid] = __builtin_amdgcn_rcpf(1.f - cc * yn);
            }
        }
        __syncthreads();

        // ---- S = Q K^T (wave tile 16x16) ----
        f32x4 acc = {0.f, 0.f, 0.f, 0.f};
#pragma unroll
        for (int ks = 0; ks < 4; ++ks) {
            int c = ks * 4 + quad;
            short8 bf = *(const short8*)(KsB + n0 * 256 + ((c ^ (n0 & 7)) * 16));
            acc = __builtin_amdgcn_mfma_f32_16x16x32_bf16(aq[ks], bf, acc, 0, 0, 0);
        }

        // ---- dist -> p (unnormalized; scores <= 0) ----
        float ynv = yn_s[col], gyv = gy_s[col];
#pragma unroll
        for (int r = 0; r < 4; ++r) {
            int row = wm * 16 + quad * 4 + r;        // C/D: row=(lane>>4)*4+reg, col=lane&15
            float diff = fmaf(-2.f, acc[r], xn_s[row] + ynv);
            float arg = fmaf(diff * gyv, rx_s[row], 1.f);
            arg = fmaxf(arg, onepe);
            float w = arg + sqrtf(fmaf(arg, arg, -1.f));
            float p = __builtin_amdgcn_exp2f(fmaf(bneg, __builtin_amdgcn_logf(w), bias2));
            *(unsigned short*)(PsB + row * PSB + col * 2) = f2bf(p);
            float s = p;
#pragma unroll
            for (int m = 1; m <= 8; m <<= 1) s += __shfl_xor(s, m, 64);
            if (lm == 0) atomicAdd(&l_row[row], s);
        }
        __syncthreads();

        // ---- coalesced P tile -> global bf16 (32x64 = 4KB = 256 uint4) ----
        if (tid < 256) {
            int row = tid >> 3, ch = tid & 7;
            uint4 pv = *(const uint4*)(PsB + row * PSB + ch * 16);
            Pws[(((bS + s0 + row) * S_ + t0) >> 3) + ch] = pv;
        }

        // ---- O += P V (wave tile 16 rows x 32 d) ----
#pragma unroll
        for (int ks = 0; ks < 2; ++ks) {
            short8 ap = *(const short8*)(PsB + (wm * 16 + lm) * PSB + ks * 64 + quad * 16);
            int c = ks * 4 + quad;
            short8 v0 = *(const short8*)(VtB + d0 * 128 + ((c ^ (d0 & 7)) * 16));
            short8 v1 = *(const short8*)(VtB + d1 * 128 + ((c ^ (d1 & 7)) * 16));
            o0 = __builtin_amdgcn_mfma_f32_16x16x32_bf16(ap, v0, o0, 0, 0, 0);
            o1 = __builtin_amdgcn_mfma_f32_16x16x32_bf16(ap, v1, o1, 0, 0, 0);
        }
    }

    // ---- combine partials: fire-and-forget device atomics ----
    float* ob = Osum + (bS + s0) * D_;
#pragma unroll
    for (int r = 0; r < 4; ++r) {
        int row = wm * 16 + quad * 4 + r;
        atomicAdd(&ob[(size_t)row * D_ + wn * 32 + lm], o0[r]);
        atomicAdd(&ob[(size_t)row * D_ + wn * 32 + 16 + lm], o1[r]);
    }
    if (tid < 32) atomicAdd(&lws[bS + s0 + tid], l_row[tid]);
}

// normalize O, exp-map at origin
__global__ __launch_bounds__(256) void hepi_kernel(const float* __restrict__ Osum,
                                                   const float* __restrict__ lws,
                                                   const float* __restrict__ cp,
                                                   float* __restrict__ hout) {
    int row = blockIdx.x * 4 + (threadIdx.x >> 6);   // one wave per row
    int lane = threadIdx.x & 63;
    const float cc = cp[0];
    const float sqrt_c = sqrtf(cc);
    float2 x2 = ((const float2*)(Osum + (size_t)row * D_))[lane];
    float linv = 1.f / lws[row];
    float x0 = x2.x * linv;
    float x1 = x2.y * linv;
    float np = x0 * x0 + x1 * x1;
#pragma unroll
    for (int m = 1; m <= 32; m <<= 1) np += __shfl_xor(np, m, 64);
    float vn = fmaxf(sqrtf(np), EPSF);
    float a = sqrt_c * vn;
    float t = 1.f - 2.f / (__expf(2.f * a) + 1.f);   // tanh(a)
    float sc = t / a;
    float2 o = {x0 * sc, x1 * sc};
    ((float2*)(hout + (size_t)row * D_))[lane] = o;
}

// expand bf16 P -> normalized fp32 W (BW roofline: ~166MB)
__global__ __launch_bounds__(256) void wnorm2_kernel(const uint4* __restrict__ Pws,
                                                     const float* __restrict__ lws,
                                                     float* __restrict__ w) {
    size_t idx = (size_t)blockIdx.x * 256 + threadIdx.x;   // uint4 index (8 bf16)
    int row = (int)(idx >> 8);                             // 256 uint4 per 2048-col row
    float linv = 1.f / lws[row];
    uint4 u = Pws[idx];
    float4 f0, f1;
    f0.x = __uint_as_float(u.x << 16) * linv;
    f0.y = __uint_as_float(u.x & 0xffff0000u) * linv;
    f0.z = __uint_as_float(u.y << 16) * linv;
    f0.w = __uint_as_float(u.y & 0xffff0000u) * linv;
    f1.x = __uint_as_float(u.z << 16) * linv;
    f1.y = __uint_as_float(u.z & 0xffff0000u) * linv;
    f1.z = __uint_as_float(u.w << 16) * linv;
    f1.w = __uint_as_float(u.w & 0xffff0000u) * linv;
    float4* out = (float4*)w + idx * 2;
    out[0] = f0;
    out[1] = f1;
}

// ===================== launch =====================

extern "C" void kernel_launch(void* const* d_in, const int* in_sizes, int n_in,
                              void* d_out, int out_size, void* d_ws, size_t ws_size,
                              hipStream_t stream) {
    const float* q    = (const float*)d_in[0];
    const float* k    = (const float*)d_in[1];
    const float* v    = (const float*)d_in[2];
    const float* c    = (const float*)d_in[3];
    const float* beta = (const float*)d_in[4];
    const float* ab   = (const float*)d_in[5];

    float* out  = (float*)d_out;
    float* hout = out;                          // (B,S,D)
    float* wout = out + (size_t)B_ * S_ * D_;   // (B,S,S)

    char* wsb = (char*)d_ws;
    float* qn  = (float*)wsb;
    float* kn  = (float*)(wsb + 32768);
    float* lws = (float*)(wsb + 65536);
    const size_t QB_OFF = 98304;
    const size_t KB_OFF = QB_OFF + 2097152;
    const size_t VT_OFF = KB_OFF + 2097152;
    const size_t OS_OFF = VT_OFF + 2097152;
    const size_t PW_OFF = OS_OFF + (size_t)B_ * S_ * D_ * 4;     // 4 MB Osum
    // NEED = PW_OFF + 32MB bf16 P  (~42.1 MB; round-3 proved ws >= 46.1 MB)

    unsigned* Qb = (unsigned*)(wsb + QB_OFF);
    unsigned* Kb = (unsigned*)(wsb + KB_OFF);
    uint4*   Vtb = (uint4*)(wsb + VT_OFF);
    float*  Osum = (float*)(wsb + OS_OFF);
    uint4*   Pws = (uint4*)(wsb + PW_OFF);

    convqk_kernel<<<4096, 256, 0, stream>>>(q, k, qn, kn, lws, Qb, Kb, Osum);
    convv_kernel<<<128, 256, 0, stream>>>(v, Vtb);
    hattn4_kernel<<<1024, 512, 0, stream>>>((const unsigned short*)Qb, (const char*)Kb,
                                            (const char*)Vtb, qn, kn, c, beta, ab,
                                            lws, Osum, Pws);
    hepi_kernel<<<2048, 256, 0, stream>>>(Osum, lws, c, hout);
    wnorm2_kernel<<<8192, 256, 0, stream>>>(Pws, lws, wout);
}